// Round 1
// baseline (40.821 us; speedup 1.0000x reference)
//
#include <hip/hip_runtime.h>

#define RR 300
#define NCLS 37
#define COUT 36
#define NW 10          // 300 bits -> 10 u32 words per mask row
#define NWAVE 5
#define SCORE_THR_C 0.1f
#define NMS_THR_C 0.4f

__global__ __launch_bounds__(320) void det_nms_kernel(
    const float* __restrict__ rois,
    const float* __restrict__ pred,
    const float* __restrict__ scr,
    const float* __restrict__ iminfo,
    float* __restrict__ out)
{
#pragma clang fp contract(off)
    const int bc  = blockIdx.x;
    const int b   = bc / COUT;
    const int c   = bc % COUT;
    const int cls = c + 1;
    const int tid = threadIdx.x;

    __shared__ float ux1[RR], uy1[RR], ux2[RR], uy2[RR], us[RR];              // original order
    __shared__ float sx1[RR], sy1[RR], sx2[RR], sy2[RR], ssc[RR], sar[RR];    // sorted order
    __shared__ int   ord[RR];
    __shared__ unsigned int mask[RR * NW];
    __shared__ unsigned char keepS[RR];
    __shared__ int   keepO[RR];
    __shared__ int   wcnt[NWAVE];
    __shared__ int   nv_sh, top_sh;

    // ---- decode boxes (exact f32 expression order as reference, no fma contraction) ----
    if (tid < RR) {
        const float* ro = rois + (size_t)(b * RR + tid) * 4;
        float x1 = ro[0], y1 = ro[1], x2 = ro[2], y2 = ro[3];
        float w  = x2 - x1 + 1.0f;
        float h  = y2 - y1 + 1.0f;
        float cx = x1 + 0.5f * w;
        float cy = y1 + 0.5f * h;
        const float* pp = pred + (size_t)(b * RR + tid) * (4 * NCLS) + 4 * cls;
        float dx = pp[0] * 0.1f;
        float dy = pp[1] * 0.1f;
        float dw = pp[2] * 0.2f;
        float dh = pp[3] * 0.2f;
        float pcx = dx * w + cx;
        float pcy = dy * h + cy;
        float pw  = expf(dw) * w;
        float ph  = expf(dh) * h;
        float Hm1 = iminfo[b * 3 + 0] - 1.0f;
        float Wm1 = iminfo[b * 3 + 1] - 1.0f;
        float px1 = fminf(fmaxf(pcx - 0.5f * pw, 0.0f), Wm1);
        float py1 = fminf(fmaxf(pcy - 0.5f * ph, 0.0f), Hm1);
        float px2 = fminf(fmaxf(pcx + 0.5f * pw, 0.0f), Wm1);
        float py2 = fminf(fmaxf(pcy + 0.5f * ph, 0.0f), Hm1);
        float sc  = iminfo[2];   // im_info[0, 2] for ALL batches (per reference)
        ux1[tid] = px1 / sc;
        uy1[tid] = py1 / sc;
        ux2[tid] = px2 / sc;
        uy2[tid] = py2 / sc;
        us[tid]  = scr[(size_t)(b * RR + tid) * NCLS + cls];
        keepS[tid] = 0;
    }
    __syncthreads();

    // ---- stable descending rank (matches jnp.argsort(-s), stable) ----
    if (tid < RR) {
        float si = us[tid];
        int rank = 0;
        for (int j = 0; j < RR; ++j) {
            float sj = us[j];                        // broadcast LDS read
            rank += (int)(sj > si) | ((int)(sj == si) & (int)(j < tid));
        }
        ord[rank] = tid;                             // unique ranks -> no race
    }
    __syncthreads();

    // ---- gather into sorted order ----
    if (tid < RR) {
        int o = ord[tid];
        float x1 = ux1[o], y1 = uy1[o], x2 = ux2[o], y2 = uy2[o];
        sx1[tid] = x1; sy1[tid] = y1; sx2[tid] = x2; sy2[tid] = y2;
        ssc[tid] = us[o];
        sar[tid] = (x2 - x1) * (y2 - y1);
    }
    __syncthreads();

    // ---- nv = #scores > THR; valid set is a PREFIX of sorted order ----
    bool v = (tid < RR) && (ssc[tid] > SCORE_THR_C);
    unsigned long long bal = __ballot(v);
    if ((tid & 63) == 0) wcnt[tid >> 6] = __popcll(bal);
    __syncthreads();
    if (tid == 0) {
        int s = 0;
        for (int w = 0; w < NWAVE; ++w) s += wcnt[w];
        nv_sh = s;
    }
    __syncthreads();
    const int nv = nv_sh;

    // ---- suppression bitmask rows, only among top-nv ----
    if (tid < nv) {
        float x1 = sx1[tid], y1 = sy1[tid], x2 = sx2[tid], y2 = sy2[tid];
        float ai = sar[tid];
        unsigned int m[NW];
        #pragma unroll
        for (int w = 0; w < NW; ++w) m[w] = 0u;
        for (int j = tid + 1; j < nv; ++j) {
            float lx = fmaxf(x1, sx1[j]);
            float ly = fmaxf(y1, sy1[j]);
            float rx = fminf(x2, sx2[j]);
            float ry = fminf(y2, sy2[j]);
            float iw = fmaxf(rx - lx, 0.0f);
            float ih = fmaxf(ry - ly, 0.0f);
            float inter = iw * ih;
            float den = ai + sar[j] - inter + 1e-12f;   // exact ref expression order
            float iou = inter / den;
            if (iou > NMS_THR_C) m[j >> 5] |= (1u << (j & 31));
        }
        #pragma unroll
        for (int w = 0; w < NW; ++w) mask[tid * NW + w] = m[w];
    }
    __syncthreads();

    // ---- serial greedy scan: iterations == #kept boxes (ctz over live mask) ----
    if (tid == 0) {
        unsigned long long live[5];
        #pragma unroll
        for (int w = 0; w < 5; ++w) {
            int lo = w * 64;
            if (nv >= lo + 64)      live[w] = ~0ull;
            else if (nv <= lo)      live[w] = 0ull;
            else                    live[w] = (~0ull) >> (64 - (nv - lo));
        }
        int first = -1;
        for (;;) {
            int i = -1;
            #pragma unroll
            for (int w = 0; w < 5; ++w) {
                if (live[w]) { i = w * 64 + __builtin_ctzll(live[w]); break; }
            }
            if (i < 0) break;
            keepS[i] = 1;
            if (first < 0) first = i;
            live[i >> 6] &= ~(1ull << (i & 63));
            const unsigned int* mr = &mask[i * NW];
            #pragma unroll
            for (int w = 0; w < 5; ++w) {
                unsigned long long mm = (unsigned long long)mr[2 * w] |
                                        ((unsigned long long)mr[2 * w + 1] << 32);
                live[w] &= ~mm;
            }
        }
        top_sh = (first >= 0) ? ord[first] : -1;   // first kept in sorted order == argmax kept
    }
    __syncthreads();

    // ---- scatter keep back to original order ----
    if (tid < RR) keepO[ord[tid]] = keepS[tid];
    __syncthreads();

    // ---- write dets: clip(>=0) * keep; class 0 gets one-hot top box ----
    if (tid < RR) {
        int kf = keepO[tid];
        if (c == 0) kf = (tid == top_sh) ? 1 : 0;
        float k = kf ? 1.0f : 0.0f;
        size_t base = (((size_t)b * COUT + c) * RR + tid) * 5;
        out[base + 0] = fmaxf(ux1[tid], 0.0f) * k;
        out[base + 1] = fmaxf(uy1[tid], 0.0f) * k;
        out[base + 2] = fmaxf(ux2[tid], 0.0f) * k;
        out[base + 3] = fmaxf(uy2[tid], 0.0f) * k;
        out[base + 4] = fmaxf(us[tid],  0.0f) * k;
    }
}

extern "C" void kernel_launch(void* const* d_in, const int* in_sizes, int n_in,
                              void* d_out, int out_size, void* d_ws, size_t ws_size,
                              hipStream_t stream) {
    const float* rois   = (const float*)d_in[0];
    const float* pred   = (const float*)d_in[1];
    const float* scores = (const float*)d_in[2];
    const float* iminfo = (const float*)d_in[3];
    float* out = (float*)d_out;
    const int B = 32;
    det_nms_kernel<<<dim3(B * COUT), dim3(320), 0, stream>>>(rois, pred, scores, iminfo, out);
}

// Round 2
// 24.331 us; speedup vs baseline: 1.6777x; 1.6777x over previous
//
#include <hip/hip_runtime.h>

#define RR 300
#define NCLS 37
#define COUT 36
#define NW 10          // 300 bits -> 10 u32 words per mask row
#define NWAVE 5
#define SCORE_THR_C 0.1f
#define NMS_THR_C 0.4f

__global__ __launch_bounds__(320) void det_nms_kernel(
    const float* __restrict__ rois,
    const float* __restrict__ pred,
    const float* __restrict__ scr,
    const float* __restrict__ iminfo,
    float* __restrict__ out)
{
#pragma clang fp contract(off)
    // --- XCD-aware bijective swizzle: hw round-robins blockIdx%8 across XCDs.
    // Map so each XCD owns 4 whole batches -> pred/scores lines hit its L2.
    const int bid = blockIdx.x;
    const int bc  = (bid & 7) * 144 + (bid >> 3);   // 1152 = 8 * 144
    const int b   = bc / COUT;
    const int c   = bc % COUT;
    const int cls = c + 1;
    const int tid = threadIdx.x;
    const int lane = tid & 63;
    const int wid  = tid >> 6;

    __shared__ float        cscore[RR + 4];          // compacted scores (+pad)
    __shared__ float4       sbox[RR];                // sorted boxes
    __shared__ float        sar[RR];                 // sorted areas
    __shared__ int          sorig[RR];               // sorted slot -> original roi
    __shared__ unsigned int mask[RR * NW];
    __shared__ unsigned char keepS[RR];              // keep per sorted slot
    __shared__ unsigned char keepG[RR];              // keep per original roi
    __shared__ int          wcnt[NWAVE];
    __shared__ int          top_sh;

    // ---- decode box into REGISTERS (exact f32 expr order as reference) ----
    float4 box = make_float4(0.f, 0.f, 0.f, 0.f);
    float  score = 0.f, area = 0.f;
    if (tid < RR) {
        const float4 ro = *reinterpret_cast<const float4*>(rois + (size_t)(b * RR + tid) * 4);
        float w  = ro.z - ro.x + 1.0f;
        float h  = ro.w - ro.y + 1.0f;
        float cx = ro.x + 0.5f * w;
        float cy = ro.y + 0.5f * h;
        const float4 pp = *reinterpret_cast<const float4*>(
            pred + (size_t)(b * RR + tid) * (4 * NCLS) + 4 * cls);
        float dx = pp.x * 0.1f;
        float dy = pp.y * 0.1f;
        float dw = pp.z * 0.2f;
        float dh = pp.w * 0.2f;
        float pcx = dx * w + cx;
        float pcy = dy * h + cy;
        float pw  = expf(dw) * w;
        float ph  = expf(dh) * h;
        float Hm1 = iminfo[b * 3 + 0] - 1.0f;
        float Wm1 = iminfo[b * 3 + 1] - 1.0f;
        float sc  = iminfo[2];   // im_info[0, 2] for ALL batches (per reference)
        box.x = fminf(fmaxf(pcx - 0.5f * pw, 0.0f), Wm1) / sc;
        box.y = fminf(fmaxf(pcy - 0.5f * ph, 0.0f), Hm1) / sc;
        box.z = fminf(fmaxf(pcx + 0.5f * pw, 0.0f), Wm1) / sc;
        box.w = fminf(fmaxf(pcy + 0.5f * ph, 0.0f), Hm1) / sc;
        score = scr[(size_t)(b * RR + tid) * NCLS + cls];
        area  = (box.z - box.x) * (box.w - box.y);
        keepS[tid] = 0;
        keepG[tid] = 0;
    }

    // ---- validity ballot + cross-wave prefix sum (compaction position) ----
    const bool v = (tid < RR) && (score > SCORE_THR_C);
    unsigned long long bal = __ballot(v);
    int inw = __popcll(bal & ((1ull << lane) - 1ull));
    if (lane == 0) wcnt[wid] = __popcll(bal);
    __syncthreads();

    int pos = inw, nvl = 0;
    #pragma unroll
    for (int w = 0; w < NWAVE; ++w) {
        int cw = wcnt[w];
        nvl += cw;
        if (w < wid) pos += cw;
    }
    const int nv = nvl;

    if (v) cscore[pos] = score;
    if (tid < 4) cscore[nv + tid] = -1.0f;           // pad so float4 rank loop needs no tail guard
    __syncthreads();

    // ---- stable descending rank among the nv valid elems (float4 LDS reads) ----
    // Valid set == prefix of full stable argsort(-s); compaction preserves
    // original-index order, so tie-break (q < pos) reproduces stability.
    int rank = 0;
    if (v) {
        const float4* cs4 = reinterpret_cast<const float4*>(cscore);
        const int n4 = (nv + 3) >> 2;
        const float si = score;
        for (int q4 = 0; q4 < n4; ++q4) {
            float4 sv = cs4[q4];
            int qb = q4 * 4;
            rank += (int)(sv.x > si) + ((int)(sv.x == si) & (int)(qb + 0 < pos));
            rank += (int)(sv.y > si) + ((int)(sv.y == si) & (int)(qb + 1 < pos));
            rank += (int)(sv.z > si) + ((int)(sv.z == si) & (int)(qb + 2 < pos));
            rank += (int)(sv.w > si) + ((int)(sv.w == si) & (int)(qb + 3 < pos));
        }
        // scatter own registers straight into sorted slot
    }
    __syncthreads();   // cscore reads done before any reuse hazards
    if (v) {
        sbox[rank]  = box;
        sar[rank]   = area;
        sorig[rank] = tid;
    }
    __syncthreads();

    // ---- suppression bitmask rows among top-nv (contiguous threads) ----
    if (tid < nv) {
        const float4 bi = sbox[tid];
        const float  ai = sar[tid];
        unsigned int m[NW];
        #pragma unroll
        for (int w = 0; w < NW; ++w) m[w] = 0u;
        for (int j = tid + 1; j < nv; ++j) {
            float4 bj = sbox[j];
            float lx = fmaxf(bi.x, bj.x);
            float ly = fmaxf(bi.y, bj.y);
            float rx = fminf(bi.z, bj.z);
            float ry = fminf(bi.w, bj.w);
            float iw = fmaxf(rx - lx, 0.0f);
            float ih = fmaxf(ry - ly, 0.0f);
            float inter = iw * ih;
            float den = ai + sar[j] - inter + 1e-12f;   // exact ref expression order
            float iou = inter / den;
            if (iou > NMS_THR_C) m[j >> 5] |= (1u << (j & 31));
        }
        #pragma unroll
        for (int w = 0; w < NW; ++w) mask[tid * NW + w] = m[w];
    }
    __syncthreads();

    // ---- serial greedy scan: iterations == #kept (ctz over live 300-bit mask) ----
    if (tid == 0) {
        unsigned long long live[5];
        #pragma unroll
        for (int w = 0; w < 5; ++w) {
            int lo = w * 64;
            if (nv >= lo + 64)      live[w] = ~0ull;
            else if (nv <= lo)      live[w] = 0ull;
            else                    live[w] = (~0ull) >> (64 - (nv - lo));
        }
        int first = -1;
        for (;;) {
            int i = -1;
            #pragma unroll
            for (int w = 0; w < 5; ++w) {
                if (live[w]) { i = w * 64 + __builtin_ctzll(live[w]); break; }
            }
            if (i < 0) break;
            keepS[i] = 1;
            if (first < 0) first = i;
            live[i >> 6] &= ~(1ull << (i & 63));
            const unsigned int* mr = &mask[i * NW];
            #pragma unroll
            for (int w = 0; w < 5; ++w) {
                unsigned long long mm = (unsigned long long)mr[2 * w] |
                                        ((unsigned long long)mr[2 * w + 1] << 32);
                live[w] &= ~mm;
            }
        }
        top_sh = first;   // first kept sorted slot == argmax of kept scores
    }
    __syncthreads();

    // ---- scatter keep back to original roi index ----
    if (tid < nv) {
        bool k = (c == 0) ? (tid == top_sh) : (keepS[tid] != 0);
        if (k) keepG[sorig[tid]] = 1;
    }
    __syncthreads();

    // ---- final write from registers (coalesced-ish, 20B/thread) ----
    if (tid < RR) {
        float k = keepG[tid] ? 1.0f : 0.0f;
        size_t base = (((size_t)b * COUT + c) * RR + tid) * 5;
        out[base + 0] = fmaxf(box.x, 0.0f) * k;
        out[base + 1] = fmaxf(box.y, 0.0f) * k;
        out[base + 2] = fmaxf(box.z, 0.0f) * k;
        out[base + 3] = fmaxf(box.w, 0.0f) * k;
        out[base + 4] = fmaxf(score, 0.0f) * k;
    }
}

extern "C" void kernel_launch(void* const* d_in, const int* in_sizes, int n_in,
                              void* d_out, int out_size, void* d_ws, size_t ws_size,
                              hipStream_t stream) {
    const float* rois   = (const float*)d_in[0];
    const float* pred   = (const float*)d_in[1];
    const float* scores = (const float*)d_in[2];
    const float* iminfo = (const float*)d_in[3];
    float* out = (float*)d_out;
    const int B = 32;
    det_nms_kernel<<<dim3(B * COUT), dim3(320), 0, stream>>>(rois, pred, scores, iminfo, out);
}